// Round 7
// baseline (590.749 us; speedup 1.0000x reference)
//
#include <hip/hip_runtime.h>

#define POOL 14
#define NUM_ROIS 512
#define NUM_ITEMS (NUM_ROIS * POOL)          // 7168
#define IMG_H 200
#define IMG_W 200
#define IMG_C 1024
#define NUM_XCD 8
#define ROIS_PER_XCD (NUM_ROIS / NUM_XCD)    // 64
#define ITEMS_PER_XCD (ROIS_PER_XCD * POOL)  // 896
#define XBINS 8
#define NBINS (IMG_H * XBINS)                // 1600
#define BINS_PER_THREAD 7                    // 256*7 = 1792 >= 1600
#define BLOCKS_PER_XCD 224                   // 1792 blocks = 7/CU, all resident
#define PERSISTENT_BLOCKS (NUM_XCD * BLOCKS_PER_XCD)

typedef float v4f __attribute__((ext_vector_type(4)));

// Sort key for a (roi, py) work item: the image row it reads + coarse x.
// Items with equal/adjacent keys read overlapping image bytes, so running
// them concurrently on one XCD turns shared segments into L2 hits.
__device__ __forceinline__ int item_key(const int* __restrict__ rois,
                                        int xcd, int i, int* out_code) {
    const int roi_in = i / POOL;
    const int py     = i - roi_in * POOL;
    const int r      = xcd * ROIS_PER_XCD + roi_in;
    const int4 box   = ((const int4*)rois)[r];  // x,y,w,h
    const float stepy = (float)box.w / (float)POOL;
    const float sy    = (float)py * stepy;
    const int y0  = (int)floorf(sy);
    const int y0c = min(max(y0, 0), box.w - 1);
    const int row = box.y + y0c;                 // 0..199
    *out_code = (r << 4) | py;
    return row * XBINS + (box.x >> 5);           // (row, x/32)
}

// Counting sort of each XCD's 896 items by (image_row, x/32).
// One block per XCD (parallel, ~8 us); perm[xcd*896 + s] = (r<<4)|py.
// Also zeroes the per-XCD work-stealing counter (same stream -> ordered).
__global__ __launch_bounds__(256) void order_kernel(
    const int* __restrict__ rois, int* __restrict__ perm,
    int* __restrict__ ctr) {
    const int xcd = blockIdx.x;
    const int tid = threadIdx.x;
    __shared__ int hist[NBINS];
    __shared__ int cnt[NBINS];
    __shared__ int partial[256];

    if (tid == 0) ctr[xcd * 32] = 0;   // one counter per XCD, own cacheline

    for (int k = tid; k < NBINS; k += 256) { hist[k] = 0; cnt[k] = 0; }
    __syncthreads();

    for (int i = tid; i < ITEMS_PER_XCD; i += 256) {
        int code;
        atomicAdd(&hist[item_key(rois, xcd, i, &code)], 1);
    }
    __syncthreads();

    // Exclusive scan of hist[NBINS]: per-thread chunk sums + Hillis-Steele.
    const int b0 = tid * BINS_PER_THREAD;
    int lsum[BINS_PER_THREAD];
    int local = 0;
    for (int j = 0; j < BINS_PER_THREAD; ++j) {
        const int k = b0 + j;
        lsum[j] = local;
        if (k < NBINS) local += hist[k];
    }
    partial[tid] = local;
    __syncthreads();
    for (int off = 1; off < 256; off <<= 1) {
        const int add = (tid >= off) ? partial[tid - off] : 0;
        __syncthreads();
        partial[tid] += add;
        __syncthreads();
    }
    const int chunk_excl = partial[tid] - local;
    for (int j = 0; j < BINS_PER_THREAD; ++j) {
        const int k = b0 + j;
        if (k < NBINS) hist[k] = chunk_excl + lsum[j];
    }
    __syncthreads();

    for (int i = tid; i < ITEMS_PER_XCD; i += 256) {
        int code;
        const int key = item_key(rois, xcd, i, &code);
        const int pos = hist[key] + atomicAdd(&cnt[key], 1);
        perm[xcd * ITEMS_PER_XCD + pos] = code;
    }
}

// Bilinear-resize one (roi, py) output row. All corner indices and lerp
// weights are BLOCK-UNIFORM, so degenerate lerps and repeated columns can
// be skipped with uniform branches, bit-exactly:
//   - need_r1 false (y1c==y0c or wy==0): res == top exactly (fma(d,0,t)=t).
//   - need_c1 false (ix1==ix0 or wx==0): top == v00 exactly.
//   - single-column cache: for step_x < 2, ix0(px+1) often equals the column
//     loaded last iteration -> reuse registers instead of reloading.
// This cuts logical read volume ~15% on average (much more for narrow ROIs),
// which is the remaining binder (reads are 4x the compulsory write stream).
__device__ __forceinline__ void process_item(
    const float* __restrict__ img, const int* __restrict__ rois,
    float* __restrict__ out, int r, int py, int c)
{
    const int4 box = ((const int4*)rois)[r];
    const int bx = box.x, by = box.y, bw = box.z, bh = box.w;

    // jnp f32 semantics: s = arange(POOL) * (dim / 14.0f)
    const float stepy = (float)bh / (float)POOL;
    const float stepx = (float)bw / (float)POOL;

    const float sy = (float)py * stepy;
    const int   y0 = (int)floorf(sy);
    const float wy = sy - (float)y0;
    const int y0c = min(max(y0, 0), bh - 1);
    const int y1c = min(max(y0 + 1, 0), bh - 1);
    const bool need_r1 = (y1c != y0c) && (wy != 0.0f);

    const float* __restrict__ r0c = img + (size_t)(by + y0c) * IMG_W * IMG_C + c;
    const float* __restrict__ r1c = img + (size_t)(by + y1c) * IMG_W * IMG_C + c;
    float* __restrict__ orow =
        out + ((size_t)r * (POOL * POOL) + (size_t)py * POOL) * IMG_C + c;

    int pcol = -1;     // column index whose values are cached
    v4f pv0, pv1;      // cached values: row0, row1

#pragma unroll
    for (int px = 0; px < POOL; ++px) {
        const float sx = (float)px * stepx;
        const int   x0 = (int)floorf(sx);
        const float wx = sx - (float)x0;
        const int ix0 = bx + min(max(x0, 0), bw - 1);
        const int ix1 = bx + min(max(x0 + 1, 0), bw - 1);
        const bool need_c1 = (ix1 != ix0) && (wx != 0.0f);

        v4f v00, v10, v01, v11;
        if (ix0 == pcol) {           // uniform: reuse last loaded column
            v00 = pv0; v10 = pv1;
        } else {
            v00 = *(const v4f*)(r0c + (size_t)ix0 * IMG_C);
            v10 = need_r1 ? *(const v4f*)(r1c + (size_t)ix0 * IMG_C) : v00;
        }
        if (need_c1) {
            v01 = *(const v4f*)(r0c + (size_t)ix1 * IMG_C);
            v11 = need_r1 ? *(const v4f*)(r1c + (size_t)ix1 * IMG_C) : v01;
        } else {
            v01 = v00; v11 = v10;
        }
        // Cache keyed by the column the values actually belong to.
        if (need_c1) { pcol = ix1; pv0 = v01; pv1 = v11; }
        else         { pcol = ix0; pv0 = v00; pv1 = v10; }

        const v4f top = v00 + (v01 - v00) * wx;
        v4f res;
        if (need_r1) {
            const v4f bot = v10 + (v11 - v10) * wx;
            res = top + (bot - top) * wy;
        } else {
            res = top;               // bit-exact: fma((bot-top),0,top)=top
        }

        // Write-once stream: non-temporal keeps it out of L1/L2.
        __builtin_nontemporal_store(res, (v4f*)(orow + (size_t)px * IMG_C));
    }
}

// PERSISTENT kernel, dynamically balanced: 1792 blocks (7/CU) all resident
// from t=0, so blockIdx%8 -> XCD holds for the whole run. Each block pulls
// the next item of its XCD's row-sorted list via an atomic counter: perfect
// balance + perfect time-adjacency of the sorted window (co-resident blocks
// hold consecutive sorted items, keeping shared image rows L2-resident).
__global__ __launch_bounds__(256) void roi_row_kernel(
    const float* __restrict__ img,   // (200,200,1024)
    const int*   __restrict__ rois,  // (512,4) x,y,w,h
    const int*   __restrict__ perm,  // row-sorted work list, or null
    int*         __restrict__ ctr,   // per-XCD work-stealing counters
    float*       __restrict__ out)   // (512,14,14,1024)
{
    const int b   = blockIdx.x;          // 0 .. 1791
    const int xcd = b & (NUM_XCD - 1);
    const int c   = threadIdx.x * 4;

    if (perm) {
        __shared__ int s_idx;
        for (;;) {
            if (threadIdx.x == 0)
                s_idx = atomicAdd(&ctr[xcd * 32], 1);
            __syncthreads();
            const int idx = s_idx;
            __syncthreads();
            if (idx >= ITEMS_PER_XCD) break;
            const int code = perm[xcd * ITEMS_PER_XCD + idx];
            process_item(img, rois, out, code >> 4, code & 15, c);
        }
    } else {
        // Fallback: static schedule without sort.
        for (int idx = b >> 3; idx < ITEMS_PER_XCD; idx += BLOCKS_PER_XCD) {
            const int roi_in = idx / POOL;
            const int py = idx - roi_in * POOL;
            process_item(img, rois, out, xcd * ROIS_PER_XCD + roi_in, py, c);
        }
    }
}

extern "C" void kernel_launch(void* const* d_in, const int* in_sizes, int n_in,
                              void* d_out, int out_size, void* d_ws, size_t ws_size,
                              hipStream_t stream) {
    const float* img  = (const float*)d_in[0];
    const int*   rois = (const int*)d_in[1];
    float*       out  = (float*)d_out;

    // Workspace layout: perm[7168] ints, then 8 counters (32-int strided).
    const size_t need = (size_t)(NUM_ITEMS + NUM_XCD * 32) * sizeof(int);
    int* perm = nullptr;
    int* ctr  = nullptr;
    if (d_ws && ws_size >= need) {
        perm = (int*)d_ws;
        ctr  = perm + NUM_ITEMS;
        order_kernel<<<NUM_XCD, 256, 0, stream>>>(rois, perm, ctr);
    }
    roi_row_kernel<<<PERSISTENT_BLOCKS, 256, 0, stream>>>(img, rois, perm, ctr, out);
}

// Round 8
// 572.633 us; speedup vs baseline: 1.0316x; 1.0316x over previous
//
#include <hip/hip_runtime.h>

#define POOL 14
#define NUM_ROIS 512
#define NUM_ITEMS (NUM_ROIS * POOL)          // 7168
#define IMG_H 200
#define IMG_W 200
#define IMG_C 1024
#define NUM_XCD 8
#define ROIS_PER_XCD (NUM_ROIS / NUM_XCD)    // 64
#define ITEMS_PER_XCD (ROIS_PER_XCD * POOL)  // 896
#define XBINS 8
#define NBINS (IMG_H * XBINS)                // 1600
#define BINS_PER_THREAD 7                    // 256*7 = 1792 >= 1600
#define BLOCKS_PER_XCD 224                   // 1792 blocks = 7/CU, all resident
#define PERSISTENT_BLOCKS (NUM_XCD * BLOCKS_PER_XCD)

typedef float v4f __attribute__((ext_vector_type(4)));

// Sort key for a (roi, py) work item: the image row it reads + coarse x.
// Items with equal/adjacent keys read overlapping image bytes, so running
// them concurrently on one XCD turns shared segments into L2 hits.
__device__ __forceinline__ int item_key(const int* __restrict__ rois,
                                        int xcd, int i, int* out_code) {
    const int roi_in = i / POOL;
    const int py     = i - roi_in * POOL;
    const int r      = xcd * ROIS_PER_XCD + roi_in;
    const int4 box   = ((const int4*)rois)[r];  // x,y,w,h
    const float stepy = (float)box.w / (float)POOL;
    const float sy    = (float)py * stepy;
    const int y0  = (int)floorf(sy);
    const int y0c = min(max(y0, 0), box.w - 1);
    const int row = box.y + y0c;                 // 0..199
    *out_code = (r << 4) | py;
    return row * XBINS + (box.x >> 5);           // (row, x/32)
}

// Counting sort of each XCD's 896 items by (image_row, x/32).
// One block per XCD (parallel, ~8 us); perm[xcd*896 + s] = (r<<4)|py.
// Also zeroes the per-XCD work-stealing counter (same stream -> ordered).
__global__ __launch_bounds__(256) void order_kernel(
    const int* __restrict__ rois, int* __restrict__ perm,
    int* __restrict__ ctr) {
    const int xcd = blockIdx.x;
    const int tid = threadIdx.x;
    __shared__ int hist[NBINS];
    __shared__ int cnt[NBINS];
    __shared__ int partial[256];

    if (tid == 0) ctr[xcd * 32] = 0;   // one counter per XCD, own cacheline

    for (int k = tid; k < NBINS; k += 256) { hist[k] = 0; cnt[k] = 0; }
    __syncthreads();

    for (int i = tid; i < ITEMS_PER_XCD; i += 256) {
        int code;
        atomicAdd(&hist[item_key(rois, xcd, i, &code)], 1);
    }
    __syncthreads();

    // Exclusive scan of hist[NBINS]: per-thread chunk sums + Hillis-Steele.
    const int b0 = tid * BINS_PER_THREAD;
    int lsum[BINS_PER_THREAD];
    int local = 0;
    for (int j = 0; j < BINS_PER_THREAD; ++j) {
        const int k = b0 + j;
        lsum[j] = local;
        if (k < NBINS) local += hist[k];
    }
    partial[tid] = local;
    __syncthreads();
    for (int off = 1; off < 256; off <<= 1) {
        const int add = (tid >= off) ? partial[tid - off] : 0;
        __syncthreads();
        partial[tid] += add;
        __syncthreads();
    }
    const int chunk_excl = partial[tid] - local;
    for (int j = 0; j < BINS_PER_THREAD; ++j) {
        const int k = b0 + j;
        if (k < NBINS) hist[k] = chunk_excl + lsum[j];
    }
    __syncthreads();

    for (int i = tid; i < ITEMS_PER_XCD; i += 256) {
        int code;
        const int key = item_key(rois, xcd, i, &code);
        const int pos = hist[key] + atomicAdd(&cnt[key], 1);
        perm[xcd * ITEMS_PER_XCD + pos] = code;
    }
}

// Bilinear-resize one (roi, py) output row: 14 px cells, each thread owns
// 4 channels. px processed in pairs: 8 INDEPENDENT dwordx4 loads issued per
// body before any use (no loop-carried state -- the R7 dedup's serialization
// cost more than its ~10% volume saving; this is the proven-best form).
__device__ __forceinline__ void process_item(
    const float* __restrict__ img, const int* __restrict__ rois,
    float* __restrict__ out, int r, int py, int c)
{
    const int4 box = ((const int4*)rois)[r];
    const int bx = box.x, by = box.y, bw = box.z, bh = box.w;

    // jnp f32 semantics: s = arange(POOL) * (dim / 14.0f)
    const float stepy = (float)bh / (float)POOL;
    const float stepx = (float)bw / (float)POOL;

    const float sy = (float)py * stepy;
    const int   y0 = (int)floorf(sy);
    const float wy = sy - (float)y0;
    const int y0c = min(max(y0, 0), bh - 1);
    const int y1c = min(max(y0 + 1, 0), bh - 1);

    const float* __restrict__ r0c = img + (size_t)(by + y0c) * IMG_W * IMG_C + c;
    const float* __restrict__ r1c = img + (size_t)(by + y1c) * IMG_W * IMG_C + c;
    float* __restrict__ orow =
        out + ((size_t)r * (POOL * POOL) + (size_t)py * POOL) * IMG_C + c;

    int ixa[POOL][2];
    float wxa[POOL];
#pragma unroll
    for (int px = 0; px < POOL; ++px) {
        const float sx = (float)px * stepx;
        const int   x0 = (int)floorf(sx);
        wxa[px]    = sx - (float)x0;
        ixa[px][0] = bx + min(max(x0, 0), bw - 1);
        ixa[px][1] = bx + min(max(x0 + 1, 0), bw - 1);
    }

#pragma unroll
    for (int it = 0; it < POOL / 2; ++it) {
        const int pa = 2 * it, pb = 2 * it + 1;

        const v4f a00 = *(const v4f*)(r0c + (size_t)ixa[pa][0] * IMG_C);
        const v4f a01 = *(const v4f*)(r0c + (size_t)ixa[pa][1] * IMG_C);
        const v4f a10 = *(const v4f*)(r1c + (size_t)ixa[pa][0] * IMG_C);
        const v4f a11 = *(const v4f*)(r1c + (size_t)ixa[pa][1] * IMG_C);
        const v4f b00 = *(const v4f*)(r0c + (size_t)ixa[pb][0] * IMG_C);
        const v4f b01 = *(const v4f*)(r0c + (size_t)ixa[pb][1] * IMG_C);
        const v4f b10 = *(const v4f*)(r1c + (size_t)ixa[pb][0] * IMG_C);
        const v4f b11 = *(const v4f*)(r1c + (size_t)ixa[pb][1] * IMG_C);

        const float wxA = wxa[pa];
        const float wxB = wxa[pb];

        const v4f topA = a00 + (a01 - a00) * wxA;
        const v4f botA = a10 + (a11 - a10) * wxA;
        const v4f resA = topA + (botA - topA) * wy;
        const v4f topB = b00 + (b01 - b00) * wxB;
        const v4f botB = b10 + (b11 - b10) * wxB;
        const v4f resB = topB + (botB - topB) * wy;

        // Write-once stream: non-temporal keeps it out of L1/L2.
        __builtin_nontemporal_store(resA, (v4f*)(orow + (size_t)pa * IMG_C));
        __builtin_nontemporal_store(resB, (v4f*)(orow + (size_t)pb * IMG_C));
    }
}

// PERSISTENT kernel, dynamically balanced: 1792 blocks (7/CU) all resident
// from t=0, so blockIdx%8 -> XCD holds for the whole run. Each block pulls
// the next item of its XCD's row-sorted list via an atomic counter: perfect
// balance + perfect time-adjacency of the sorted window (co-resident blocks
// hold consecutive sorted items, keeping shared image rows L2-resident).
__global__ __launch_bounds__(256) void roi_row_kernel(
    const float* __restrict__ img,   // (200,200,1024)
    const int*   __restrict__ rois,  // (512,4) x,y,w,h
    const int*   __restrict__ perm,  // row-sorted work list, or null
    int*         __restrict__ ctr,   // per-XCD work-stealing counters
    float*       __restrict__ out)   // (512,14,14,1024)
{
    const int b   = blockIdx.x;          // 0 .. 1791
    const int xcd = b & (NUM_XCD - 1);
    const int c   = threadIdx.x * 4;

    if (perm) {
        __shared__ int s_idx;
        for (;;) {
            if (threadIdx.x == 0)
                s_idx = atomicAdd(&ctr[xcd * 32], 1);
            __syncthreads();
            const int idx = s_idx;
            __syncthreads();
            if (idx >= ITEMS_PER_XCD) break;
            const int code = perm[xcd * ITEMS_PER_XCD + idx];
            process_item(img, rois, out, code >> 4, code & 15, c);
        }
    } else {
        // Fallback: static schedule without sort.
        for (int idx = b >> 3; idx < ITEMS_PER_XCD; idx += BLOCKS_PER_XCD) {
            const int roi_in = idx / POOL;
            const int py = idx - roi_in * POOL;
            process_item(img, rois, out, xcd * ROIS_PER_XCD + roi_in, py, c);
        }
    }
}

extern "C" void kernel_launch(void* const* d_in, const int* in_sizes, int n_in,
                              void* d_out, int out_size, void* d_ws, size_t ws_size,
                              hipStream_t stream) {
    const float* img  = (const float*)d_in[0];
    const int*   rois = (const int*)d_in[1];
    float*       out  = (float*)d_out;

    // Workspace layout: perm[7168] ints, then 8 counters (32-int strided).
    const size_t need = (size_t)(NUM_ITEMS + NUM_XCD * 32) * sizeof(int);
    int* perm = nullptr;
    int* ctr  = nullptr;
    if (d_ws && ws_size >= need) {
        perm = (int*)d_ws;
        ctr  = perm + NUM_ITEMS;
        order_kernel<<<NUM_XCD, 256, 0, stream>>>(rois, perm, ctr);
    }
    roi_row_kernel<<<PERSISTENT_BLOCKS, 256, 0, stream>>>(img, rois, perm, ctr, out);
}